// Round 10
// baseline (222.208 us; speedup 1.0000x reference)
//
#include <hip/hip_runtime.h>
#include <hip/hip_bf16.h>

#define B_  16
#define LQ  2048
#define LS  2048
#define DD  512
#define BQ  128           // block q-extent (halved vs R9 -> 2 blocks/CU)
#define BS  256
#define BK  64
#define HK  32            // half-K granularity of the prefetch ring
#define NSB (LS / BS)     // 8 s-blocks total
#define NKC (DD / BK)     // 8 k-stages per s-block
#define NSPLIT 4

static_assert(NKC == 8, "stage math assumes NKC==8");

typedef short bf16x8 __attribute__((ext_vector_type(8)));
typedef float f32x4  __attribute__((ext_vector_type(4)));

// async global->LDS, 16B per lane. LDS dest = wave-uniform base + lane*16.
__device__ __forceinline__ void load_lds16(const void* g, void* l) {
  __builtin_amdgcn_global_load_lds((const __attribute__((address_space(1))) void*)g,
                                   (__attribute__((address_space(3))) void*)l,
                                   16, 0, 0);
}

__device__ __forceinline__ unsigned short f2bf(float f) {
  union { float f; unsigned int u; } v; v.f = f;
  unsigned int r = v.u + 0x7fffu + ((v.u >> 16) & 1u);  // RNE
  return (unsigned short)(r >> 16);
}

// Grid-stride cvt: 2048 blocks (first half Q, second half S).
__global__ __launch_bounds__(256) void cvt_kernel(const float* __restrict__ Q,
                                                  const float* __restrict__ S,
                                                  unsigned short* __restrict__ Qw,
                                                  unsigned short* __restrict__ Sw) {
  const int half = gridDim.x >> 1;
  int blk = blockIdx.x;
  const float* src; unsigned short* dst;
  if (blk < half) { src = Q; dst = Qw; } else { src = S; dst = Sw; blk -= half; }
  const size_t n4 = (size_t)B_ * LQ * DD / 4;
  const size_t stride = (size_t)half * 256;
  for (size_t i = (size_t)blk * 256 + threadIdx.x; i < n4; i += stride) {
    float4 f = ((const float4*)src)[i];
    ushort4 u;
    u.x = f2bf(f.x); u.y = f2bf(f.y); u.z = f2bf(f.z); u.w = f2bf(f.w);
    ((ushort4*)dst)[i] = u;
  }
}

// score[b,q] = sum_s softmax(l)[s]*l[s],  l[s] = Q[b,q,:].S[b,s,:]
// MFMA 16x16x32: A = S-tile (M=s), B = Q-tile^T (N=q) -> C[row=s][col=q]
// C layout: col = lane&15, row = (lane>>4)*4 + reg  [m89/m91]
//
// Round-10: MfmaUtil pinned at ~33% in ALL 1-block/CU schedules (R2/R4/R6/
// R8/R9): each barrier locksteps both waves of a SIMD into {LDS-burst |
// MFMA} phases that add serially (measured 3124 cy/half vs 1241 MFMA +
// ~600 LDS). Fix = second independent scheduling domain: 2 blocks/CU.
// Per-wave geometry UNCHANGED from R9 (128s x 64q, 12 ds_read -> 32 MFMA,
// 0-conflict (row>>1)&3 swizzle, counted-vmcnt ring, L2-locality decode);
// only the block q-extent halves: BQ=128, 4 waves, ring 3 slots = 72 KiB
// -> 2 blocks/CU. Block A's barrier stall overlaps block B's MFMAs.
// Depth-2 prefetch (vmcnt(6)) over L2-resident data (~300cy) is ample.
// Extra: all 12 ds_reads issued up-front, counted lgkmcnt(4) (issue order
// pinned by sched_barrier) so cluster-1 reads hide under cluster-0 MFMA.
__global__ __launch_bounds__(256, 2) void attn_kernel(const unsigned short* __restrict__ Qw,
                                                      const unsigned short* __restrict__ Sw,
                                                      float* __restrict__ out,
                                                      float* __restrict__ pm,
                                                      float* __restrict__ pse,
                                                      float* __restrict__ psel,
                                                      int nsplit) {
  // ring of 3 half-K slots: Q 128x32x2B = 8 KiB, S 256x32x2B = 16 KiB
  __shared__ __align__(16) unsigned short sQh[3][BQ * HK];  // 24 KiB
  __shared__ __align__(16) unsigned short sSh[3][BS * HK];  // 48 KiB

  // --- chunked XCD swizzle (bijective: nwg = 256*nsplit divisible by 8) ---
  const int pid = blockIdx.x + (blockIdx.y << 4) + (blockIdx.z << 8);
  const int nch = (nsplit << 8) >> 3;          // nwg / 8
  const int lid = (pid & 7) * nch + (pid >> 3);
  // locality decode: qb fastest, then spl, then b. Concurrent set per XCD =
  // one b's Q (2 MB) + its S (2 MB) = 4 MB = L2-resident.
  const int qb   = lid & 15;                   // gridDim.x == 16
  const int rest = lid >> 4;
  const int spl  = rest & (nsplit - 1);        // nsplit in {1,4}
  const int b    = rest >> (nsplit == 4 ? 2 : 0);

  const int tid  = threadIdx.x;
  const int w    = tid >> 6;      // 0..3
  const int lane = tid & 63;
  const int h    = w & 1;         // s-half: rows [h*128, h*128+128)
  const int g    = w >> 1;        // q-half: cols [g*64, g*64+64)
  const int col  = lane & 15;
  const int quad = lane >> 4;

  const int q0 = qb * BQ;
  const unsigned short* Qb = Qw + (size_t)b * LQ * DD;
  const unsigned short* Sb = Sw + (size_t)b * LS * DD;

  float mst[4] = { -INFINITY, -INFINITY, -INFINITY, -INFINITY };
  float se[4]  = { 0.f, 0.f, 0.f, 0.f };
  float sel[4] = { 0.f, 0.f, 0.f, 0.f };

  f32x4 acc[8][4];   // [s-tile][q-tile] = 128 regs
#pragma unroll
  for (int st = 0; st < 8; ++st)
#pragma unroll
    for (int qt = 0; qt < 4; ++qt)
      acc[st][qt] = (f32x4){0.f, 0.f, 0.f, 0.f};

  // staging: lane l -> row (l>>2), slot (l&3); slot j of row r holds global
  // chunk j ^ ((r>>1)&3) -> source chunk = (l&3) ^ ((l>>3)&3)  [R9: 0 conf]
  const int cc8 = (((lane & 3) ^ ((lane >> 3) & 3)) * 8);
  const int rl  = lane >> 2;                 // row-within-16 for staging
  // read-side slot XOR: s(row) = (row>>1)&3 = (col>>1)&3 (bases %16 == 0)
  const int koq = ((quad ^ ((col >> 1) & 3)) * 8);

  const int sbs = spl * (NSB / nsplit);
  const int nst = (NSB / nsplit) * NKC;      // stages (K=64)
  const int U   = nst * 2;                   // halves (K=32)

  // every wave stages Q rows [w*32,+32) (2 loads) and S rows [w*64,+64)
  // (4 loads): 6 gl_lds/wave/half, 1 KiB linear each.
  auto issue_half = [&](int u, int slot) {
    const int t  = u >> 1;
    const int k0 = (t & 7) * 64 + (u & 1) * 32;
    const int sb = sbs + (t >> 3);
    const unsigned short* gq = Qb + (size_t)(q0 + w * 32 + rl) * DD + k0 + cc8;
    unsigned short* lq = &sQh[slot][(w * 32) * HK];
#pragma unroll
    for (int i = 0; i < 2; ++i)
      load_lds16(gq + (size_t)i * 16 * DD, lq + i * 16 * HK);
    const unsigned short* gs = Sb + (size_t)(sb * BS + w * 64 + rl) * DD + k0 + cc8;
    unsigned short* ls = &sSh[slot][(w * 64) * HK];
#pragma unroll
    for (int i = 0; i < 4; ++i)
      load_lds16(gs + (size_t)i * 16 * DD, ls + i * 16 * HK);
  };

  // prologue: fill ring depth 2
  issue_half(0, 0);
  issue_half(1, 1);
  int cs = 0;  // slot of current half u

#pragma unroll 1
  for (int u = 0; u < U; ++u) {
    // own 6 loads of half u retired; u+1's 6 keep flying (depth 2)
    if (u + 1 < U) asm volatile("s_waitcnt vmcnt(6)" ::: "memory");
    else           asm volatile("s_waitcnt vmcnt(0)" ::: "memory");
    __builtin_amdgcn_s_barrier();             // half u visible CU-wide

    const unsigned short* bq = &sQh[cs][0];
    const unsigned short* bs = &sSh[cs][0];

    bf16x8 aq[4], as0[4], as1[4];
    // first 8 reads (cluster-0 operands)
#pragma unroll
    for (int qt = 0; qt < 4; ++qt)
      aq[qt] = *(const bf16x8*)&bq[(g * 64 + qt * 16 + col) * HK + koq];
#pragma unroll
    for (int st = 0; st < 4; ++st)
      as0[st] = *(const bf16x8*)&bs[(h * 128 + st * 16 + col) * HK + koq];
    __builtin_amdgcn_sched_barrier(0);        // pin issue order: 8 then 4
    // last 4 reads (cluster-1 operands)
#pragma unroll
    for (int st = 0; st < 4; ++st)
      as1[st] = *(const bf16x8*)&bs[(h * 128 + (4 + st) * 16 + col) * HK + koq];
    {  // prefetch half u+2 into freed slot (readers retired pre-barrier)
      int is = cs + 2; if (is >= 3) is -= 3;
      if (u + 2 < U) issue_half(u + 2, is);
    }
    asm volatile("s_waitcnt lgkmcnt(4)" ::: "memory");  // first 8 landed
    __builtin_amdgcn_sched_barrier(0);
    __builtin_amdgcn_s_setprio(1);
#pragma unroll
    for (int qt = 0; qt < 4; ++qt)
#pragma unroll
      for (int st = 0; st < 4; ++st)
        acc[st][qt] = __builtin_amdgcn_mfma_f32_16x16x32_bf16(as0[st], aq[qt], acc[st][qt], 0, 0, 0);
    __builtin_amdgcn_s_setprio(0);
    asm volatile("s_waitcnt lgkmcnt(0)" ::: "memory");  // last 4 (hidden under MFMA)
    __builtin_amdgcn_sched_barrier(0);
    __builtin_amdgcn_s_setprio(1);
#pragma unroll
    for (int qt = 0; qt < 4; ++qt)
#pragma unroll
      for (int st = 0; st < 4; ++st)
        acc[4 + st][qt] = __builtin_amdgcn_mfma_f32_16x16x32_bf16(as1[st], aq[qt], acc[4 + st][qt], 0, 0, 0);
    __builtin_amdgcn_s_setprio(0);

    if ((u & (2 * NKC - 1)) == 2 * NKC - 1) {
      // online softmax-weighted-mean over this wave's 128-s rows; next
      // s-block's halves already in flight (no barrier until pair top)
#pragma unroll
      for (int qt = 0; qt < 4; ++qt) {
        float lmax = mst[qt];
#pragma unroll
        for (int st = 0; st < 8; ++st)
#pragma unroll
          for (int r = 0; r < 4; ++r)
            lmax = fmaxf(lmax, acc[st][qt][r]);
        lmax = fmaxf(lmax, __shfl_xor(lmax, 16, 64));
        lmax = fmaxf(lmax, __shfl_xor(lmax, 32, 64));
        float alpha = __expf(mst[qt] - lmax);  // exp(-inf)=0 on first block
        float pe = 0.f, pel = 0.f;
#pragma unroll
        for (int st = 0; st < 8; ++st)
#pragma unroll
          for (int r = 0; r < 4; ++r) {
            float l = acc[st][qt][r];
            float e = __expf(l - lmax);
            pe += e;
            pel = fmaf(e, l, pel);
          }
        pe  += __shfl_xor(pe, 16, 64);  pe  += __shfl_xor(pe, 32, 64);
        pel += __shfl_xor(pel, 16, 64); pel += __shfl_xor(pel, 32, 64);
        se[qt]  = fmaf(se[qt],  alpha, pe);
        sel[qt] = fmaf(sel[qt], alpha, pel);
        mst[qt] = lmax;
#pragma unroll
        for (int st = 0; st < 8; ++st)
          acc[st][qt] = (f32x4){0.f, 0.f, 0.f, 0.f};
      }
    }
    cs = (cs + 1 == 3) ? 0 : cs + 1;
  }

  // merge the two s-halves (h=0,1) per q-column via LDS, then write
  __syncthreads();
  float* red = (float*)&sQh[0][0];   // 3 KiB, ring no longer needed
  if (quad == 0) {
#pragma unroll
    for (int qt = 0; qt < 4; ++qt) {
      int qq = g * 64 + qt * 16 + col;           // 0..127
      red[h * 128 + qq]       = mst[qt];
      red[256 + h * 128 + qq] = se[qt];
      red[512 + h * 128 + qq] = sel[qt];
    }
  }
  __syncthreads();
  if (h == 0 && quad == 0) {
#pragma unroll
    for (int qt = 0; qt < 4; ++qt) {
      int qq = g * 64 + qt * 16 + col;
      float m0 = red[qq],       m1 = red[128 + qq];
      float M  = fmaxf(m0, m1);
      float a0 = __expf(m0 - M), a1 = __expf(m1 - M);
      float SE  = red[256 + qq] * a0 + red[256 + 128 + qq] * a1;
      float SEL = red[512 + qq] * a0 + red[512 + 128 + qq] * a1;
      size_t qi = (size_t)b * LQ + q0 + qq;
      if (nsplit == 1) {
        out[qi] = SEL / SE;
      } else {
        pm[qi * NSPLIT + spl]   = M;
        pse[qi * NSPLIT + spl]  = SE;
        psel[qi * NSPLIT + spl] = SEL;
      }
    }
  }
}

__global__ __launch_bounds__(256) void combine_kernel(const float* __restrict__ pm,
                                                      const float* __restrict__ pse,
                                                      const float* __restrict__ psel,
                                                      float* __restrict__ out) {
  int i = blockIdx.x * blockDim.x + threadIdx.x;
  if (i >= B_ * LQ) return;
  float M = -INFINITY;
#pragma unroll
  for (int s = 0; s < NSPLIT; ++s) M = fmaxf(M, pm[i * NSPLIT + s]);
  float SE = 0.f, SEL = 0.f;
#pragma unroll
  for (int s = 0; s < NSPLIT; ++s) {
    float a = __expf(pm[i * NSPLIT + s] - M);
    SE  = fmaf(pse[i * NSPLIT + s],  a, SE);
    SEL = fmaf(psel[i * NSPLIT + s], a, SEL);
  }
  out[i] = SEL / SE;
}

// fp32 fallback (correctness insurance if ws too small)
__global__ __launch_bounds__(256) void fallback_kernel(const float* __restrict__ Q,
                                                       const float* __restrict__ S,
                                                       float* __restrict__ out) {
  __shared__ float qv[DD];
  __shared__ float red[256];
  const int b = blockIdx.y, qi = blockIdx.x, tid = threadIdx.x;
  const float* qrow = Q + ((size_t)b * LQ + qi) * DD;
  for (int d = tid; d < DD; d += 256) qv[d] = qrow[d];
  __syncthreads();
  const float* Sb = S + (size_t)b * LS * DD;
  float m = -INFINITY, se = 0.f, sel = 0.f;
  for (int s = tid; s < LS; s += 256) {
    const float* srow = Sb + (size_t)s * DD;
    float dot = 0.f;
    for (int d = 0; d < DD; ++d) dot = fmaf(qv[d], srow[d], dot);
    float mn = fmaxf(m, dot);
    float a = __expf(m - mn);
    float e = __expf(dot - mn);
    se  = se * a + e;
    sel = sel * a + e * dot;
    m = mn;
  }
  red[tid] = m; __syncthreads();
  for (int o = 128; o > 0; o >>= 1) { if (tid < o) red[tid] = fmaxf(red[tid], red[tid + o]); __syncthreads(); }
  float M = red[0]; __syncthreads();
  float a = __expf(m - M); se *= a; sel *= a;
  red[tid] = se; __syncthreads();
  for (int o = 128; o > 0; o >>= 1) { if (tid < o) red[tid] += red[tid + o]; __syncthreads(); }
  float SE = red[0]; __syncthreads();
  red[tid] = sel; __syncthreads();
  for (int o = 128; o > 0; o >>= 1) { if (tid < o) red[tid] += red[tid + o]; __syncthreads(); }
  float SEL = red[0];
  if (tid == 0) out[(size_t)b * LQ + qi] = SEL / SE;
}

extern "C" void kernel_launch(void* const* d_in, const int* in_sizes, int n_in,
                              void* d_out, int out_size, void* d_ws, size_t ws_size,
                              hipStream_t stream) {
  const float* Q = (const float*)d_in[0];
  const float* S = (const float*)d_in[1];
  float* out = (float*)d_out;
  const size_t nelem = (size_t)B_ * LQ * DD;                    // 16.78M / tensor
  const size_t need_base  = 2 * nelem * sizeof(unsigned short); // 67 MiB
  const size_t part_elems = (size_t)B_ * LQ * NSPLIT;
  const size_t need_split = need_base + 3 * part_elems * sizeof(float);

  if (ws_size >= need_base) {
    unsigned short* Qw = (unsigned short*)d_ws;
    unsigned short* Sw = Qw + nelem;
    cvt_kernel<<<2048, 256, 0, stream>>>(Q, S, Qw, Sw);
    if (ws_size >= need_split) {
      float* pm   = (float*)(Sw + nelem);
      float* pse  = pm + part_elems;
      float* psel = pse + part_elems;
      attn_kernel<<<dim3(LQ / BQ, B_, NSPLIT), 256, 0, stream>>>(Qw, Sw, out, pm, pse, psel, NSPLIT);
      combine_kernel<<<(B_ * LQ + 255) / 256, 256, 0, stream>>>(pm, pse, psel, out);
    } else {
      attn_kernel<<<dim3(LQ / BQ, B_, 1), 256, 0, stream>>>(Qw, Sw, out, nullptr, nullptr, nullptr, 1);
    }
  } else {
    fallback_kernel<<<dim3(LQ, B_), 256, 0, stream>>>(Q, S, out);
  }
}